// Round 1
// baseline (264.922 us; speedup 1.0000x reference)
//
#include <hip/hip_runtime.h>
#include <cmath>

#define D_IN 256
#define H_DIM 128
#define NUM_GRAPHS 1024

typedef __attribute__((ext_vector_type(8))) __bf16 bf16x8;
typedef __attribute__((ext_vector_type(4))) float f32x4;

// ---------------------------------------------------------------------------
// Kernel W: pack W1 (f32, row-major [256][128]) into bf16 MFMA B-fragment order.
// For mfma_f32_16x16x32_bf16, B-frag: lane l holds B[k][n] with n = nt*16 + (l&15),
// k = ks*32 + (l>>4)*8 + i, i=0..7. Packed so each lane reads one contiguous 16B.
// packed[((nt*8 + ks)*64 + l)*8 + i]
// ---------------------------------------------------------------------------
__global__ void pack_w1(const float* __restrict__ W1, ushort* __restrict__ packed) {
    int tid = blockIdx.x * 256 + threadIdx.x;
    if (tid >= 8 * 8 * 64) return;
    int nt = tid >> 9;
    int ks = (tid >> 6) & 7;
    int l = tid & 63;
    int col = nt * 16 + (l & 15);
    int kbase = ks * 32 + ((l >> 4) & 3) * 8;
#pragma unroll
    for (int i = 0; i < 8; ++i) {
        float v = W1[(size_t)(kbase + i) * H_DIM + col];
        __bf16 b = (__bf16)v;
        packed[(size_t)tid * 8 + i] = *reinterpret_cast<ushort*>(&b);
    }
}

// ---------------------------------------------------------------------------
// Kernel A: scores[i] = relu(x[i]@W1 + b1) @ W2 + b2  via bf16 MFMA.
// Block = 256 threads = 4 waves; each wave does 16 rows x 128 cols, K=256.
// ---------------------------------------------------------------------------
__global__ __launch_bounds__(256) void score_kernel(
    const float* __restrict__ x, const ushort* __restrict__ w1p,
    const float* __restrict__ b1, const float* __restrict__ W2,
    const float* __restrict__ b2, float* __restrict__ scores, int N) {
    int l = threadIdx.x & 63;
    int w = threadIdx.x >> 6;
    long long rowBase = (long long)blockIdx.x * 64 + w * 16;

    int r = l & 15;       // A-frag row within tile / B-frag col within ntile
    int kg = l >> 4;      // 0..3

    long long arow = rowBase + r;
    if (arow >= N) arow = N - 1;
    const float* xptr = x + arow * D_IN + kg * 8;

    f32x4 acc[8] = {};

#pragma unroll
    for (int ks = 0; ks < 8; ++ks) {
        f32x4 a0 = *(const f32x4*)(xptr + ks * 32);
        f32x4 a1 = *(const f32x4*)(xptr + ks * 32 + 4);
        bf16x8 af;
#pragma unroll
        for (int i = 0; i < 4; ++i) {
            af[i] = (__bf16)a0[i];
            af[i + 4] = (__bf16)a1[i];
        }
#pragma unroll
        for (int nt = 0; nt < 8; ++nt) {
            bf16x8 bf = *(const bf16x8*)(w1p + ((size_t)(nt * 8 + ks) * 64 + l) * 8);
            acc[nt] = __builtin_amdgcn_mfma_f32_16x16x32_bf16(af, bf, acc[nt], 0, 0, 0);
        }
    }

    // Epilogue: h = relu(acc + b1); score = h @ W2 + b2.
    // C/D layout: col = nt*16 + (l&15), row = (l>>4)*4 + reg.
    float w2v[8], b1v[8];
#pragma unroll
    for (int nt = 0; nt < 8; ++nt) {
        int c = nt * 16 + r;
        w2v[nt] = W2[c];
        b1v[nt] = b1[c];
    }
    float bb = b2[0];
#pragma unroll
    for (int reg = 0; reg < 4; ++reg) {
        float p = 0.f;
#pragma unroll
        for (int nt = 0; nt < 8; ++nt) {
            float h = acc[nt][reg] + b1v[nt];
            h = fmaxf(h, 0.f);
            p += h * w2v[nt];
        }
        // reduce across the 16 lanes sharing this row
        p += __shfl_xor(p, 1, 64);
        p += __shfl_xor(p, 2, 64);
        p += __shfl_xor(p, 4, 64);
        p += __shfl_xor(p, 8, 64);
        long long row = rowBase + kg * 4 + reg;
        if (r == 0 && row < N) scores[row] = p + bb;
    }
}

// ---------------------------------------------------------------------------
// Online-softmax partials: per block (m_b, z_b) with z = sum exp(s - m).
// ---------------------------------------------------------------------------
__device__ inline void sm_combine(float& m, float& z, float m2, float z2) {
    float M = fmaxf(m, m2);
    if (M == -INFINITY) { m = M; z = 0.f; return; }
    z = z * __expf(m - M) + z2 * __expf(m2 - M);
    m = M;
}

__global__ __launch_bounds__(256) void softmax_part(
    const float* __restrict__ scores, int N,
    float* __restrict__ pm, float* __restrict__ pz) {
    int tid = blockIdx.x * 256 + threadIdx.x;
    int stride = gridDim.x * 256;
    float m = -INFINITY, z = 0.f;
    for (int i = tid; i < N; i += stride) {
        float s = scores[i];
        if (s > m) { z = z * __expf(m - s) + 1.f; m = s; }
        else z += __expf(s - m);
    }
    __shared__ float sm[256], sz[256];
    sm[threadIdx.x] = m;
    sz[threadIdx.x] = z;
    __syncthreads();
    for (int off = 128; off > 0; off >>= 1) {
        if (threadIdx.x < off) {
            float mm = sm[threadIdx.x], zz = sz[threadIdx.x];
            sm_combine(mm, zz, sm[threadIdx.x + off], sz[threadIdx.x + off]);
            sm[threadIdx.x] = mm;
            sz[threadIdx.x] = zz;
        }
        __syncthreads();
    }
    if (threadIdx.x == 0) { pm[blockIdx.x] = sm[0]; pz[blockIdx.x] = sz[0]; }
}

__global__ __launch_bounds__(256) void softmax_merge(
    const float* __restrict__ pm, const float* __restrict__ pz, int nPart,
    float* __restrict__ MZ) {
    float m = -INFINITY, z = 0.f;
    for (int i = threadIdx.x; i < nPart; i += 256)
        sm_combine(m, z, pm[i], pz[i]);
    __shared__ float sm[256], sz[256];
    sm[threadIdx.x] = m;
    sz[threadIdx.x] = z;
    __syncthreads();
    for (int off = 128; off > 0; off >>= 1) {
        if (threadIdx.x < off) {
            float mm = sm[threadIdx.x], zz = sz[threadIdx.x];
            sm_combine(mm, zz, sm[threadIdx.x + off], sz[threadIdx.x + off]);
            sm[threadIdx.x] = mm;
            sz[threadIdx.x] = zz;
        }
        __syncthreads();
    }
    if (threadIdx.x == 0) { MZ[0] = sm[0]; MZ[1] = 1.f / sz[0]; }
}

// ---------------------------------------------------------------------------
// Pool kernel: one block per graph. Sorted batch -> segment via binary search.
// Thread layout: cg = tid>>6 picks node-phase (4 nodes in flight),
// c0 = (tid&63)*4 picks a float4 column slice. Weights staged in LDS.
// ---------------------------------------------------------------------------
__device__ inline int lower_bound_i(const int* __restrict__ arr, int n, int val) {
    int lo = 0, hi = n;
    while (lo < hi) {
        int mid = (lo + hi) >> 1;
        if (arr[mid] < val) lo = mid + 1; else hi = mid;
    }
    return lo;
}

__global__ __launch_bounds__(256) void pool_kernel(
    const float* __restrict__ x, const float* __restrict__ scores,
    const int* __restrict__ batch, const float* __restrict__ MZ,
    float* __restrict__ out, int N) {
    int g = blockIdx.x;
    __shared__ int sb[2];
    if (threadIdx.x < 2) sb[threadIdx.x] = lower_bound_i(batch, N, g + threadIdx.x);
    __syncthreads();
    int start = sb[0], end = sb[1];
    int cnt = end - start;
    float M = MZ[0], invZ = MZ[1];

    int cg = threadIdx.x >> 6;
    int c0 = (threadIdx.x & 63) * 4;

    float asum[4] = {0.f, 0.f, 0.f, 0.f};
    float ssum[4] = {0.f, 0.f, 0.f, 0.f};
    float mx[4] = {-INFINITY, -INFINITY, -INFINITY, -INFINITY};

    __shared__ float wbuf[256];
    for (int base = start; base < end; base += 256) {
        int mcnt = min(256, end - base);
        if (threadIdx.x < mcnt)
            wbuf[threadIdx.x] = __expf(scores[base + threadIdx.x] - M) * invZ;
        __syncthreads();
        for (int i = cg; i < mcnt; i += 4) {
            f32x4 v = *(const f32x4*)(x + (size_t)(base + i) * D_IN + c0);
            float wgt = wbuf[i];
#pragma unroll
            for (int j = 0; j < 4; ++j) {
                asum[j] += v[j] * wgt;
                ssum[j] += v[j];
                mx[j] = fmaxf(mx[j], v[j]);
            }
        }
        __syncthreads();
    }

    // reduce the 4 node-phases
    __shared__ f32x4 red[256];
    f32x4 t;
#pragma unroll
    for (int j = 0; j < 4; ++j) t[j] = asum[j];
    red[threadIdx.x] = t;
    __syncthreads();
    f32x4 attnv, maxv, sumv;
    if (cg == 0) {
        attnv = red[threadIdx.x];
#pragma unroll
        for (int k = 1; k < 4; ++k) {
            f32x4 o = red[threadIdx.x + 64 * k];
#pragma unroll
            for (int j = 0; j < 4; ++j) attnv[j] += o[j];
        }
    }
    __syncthreads();
#pragma unroll
    for (int j = 0; j < 4; ++j) t[j] = ssum[j];
    red[threadIdx.x] = t;
    __syncthreads();
    if (cg == 0) {
        sumv = red[threadIdx.x];
#pragma unroll
        for (int k = 1; k < 4; ++k) {
            f32x4 o = red[threadIdx.x + 64 * k];
#pragma unroll
            for (int j = 0; j < 4; ++j) sumv[j] += o[j];
        }
    }
    __syncthreads();
#pragma unroll
    for (int j = 0; j < 4; ++j) t[j] = mx[j];
    red[threadIdx.x] = t;
    __syncthreads();
    if (cg == 0) {
        maxv = red[threadIdx.x];
#pragma unroll
        for (int k = 1; k < 4; ++k) {
            f32x4 o = red[threadIdx.x + 64 * k];
#pragma unroll
            for (int j = 0; j < 4; ++j) maxv[j] = fmaxf(maxv[j], o[j]);
        }
    }

    if (cg == 0) {
        size_t ob = (size_t)g * (3 * D_IN);
        float invc = 1.f / (float)max(cnt, 1);
        *(f32x4*)(out + ob + c0) = attnv;
        *(f32x4*)(out + ob + D_IN + c0) = maxv;
        f32x4 meanv;
#pragma unroll
        for (int j = 0; j < 4; ++j) meanv[j] = sumv[j] * invc;
        *(f32x4*)(out + ob + 2 * D_IN + c0) = meanv;
    }
}

// ---------------------------------------------------------------------------
extern "C" void kernel_launch(void* const* d_in, const int* in_sizes, int n_in,
                              void* d_out, int out_size, void* d_ws, size_t ws_size,
                              hipStream_t stream) {
    const float* x = (const float*)d_in[0];
    const float* W1 = (const float*)d_in[1];
    const float* b1 = (const float*)d_in[2];
    const float* W2 = (const float*)d_in[3];
    const float* b2 = (const float*)d_in[4];
    const int* batch = (const int*)d_in[5];
    int N = in_sizes[0] / D_IN;
    float* out = (float*)d_out;

    char* ws = (char*)d_ws;
    size_t off = 0;
    float* scores = (float*)(ws + off);
    off += (((size_t)N * 4) + 255) & ~(size_t)255;
    ushort* w1p = (ushort*)(ws + off);
    off += 8 * 8 * 64 * 8 * sizeof(ushort);  // 65536
    float* pm = (float*)(ws + off);
    off += 1024 * 4;
    float* pz = (float*)(ws + off);
    off += 1024 * 4;
    float* MZ = (float*)(ws + off);
    off += 256;

    pack_w1<<<16, 256, 0, stream>>>(W1, w1p);

    int nblk = (N + 63) / 64;
    score_kernel<<<nblk, 256, 0, stream>>>(x, w1p, b1, W2, b2, scores, N);

    softmax_part<<<1024, 256, 0, stream>>>(scores, N, pm, pz);
    softmax_merge<<<1, 256, 0, stream>>>(pm, pz, 1024, MZ);

    pool_kernel<<<NUM_GRAPHS, 256, 0, stream>>>(x, scores, batch, MZ, out, N);
}